// Round 1
// baseline (321.665 us; speedup 1.0000x reference)
//
#include <hip/hip_runtime.h>

#define DEV __device__ __forceinline__

typedef __attribute__((ext_vector_type(8))) short bf16x8;
typedef __attribute__((ext_vector_type(4))) float f32x4;

// ---------- bf16 helpers (bit-level, RNE) ----------
DEV unsigned short f2bf(float f) {
  union { float f; unsigned int u; } v; v.f = f;
  unsigned int u = v.u;
  unsigned int r = (u + 0x7fffu + ((u >> 16) & 1u)) >> 16;
  return (unsigned short)r;
}
DEV float bf2f(unsigned short h) {
  union { unsigned int u; float f; } v; v.u = ((unsigned int)h) << 16;
  return v.f;
}

// ---------- fp32 -> bf16 convert (vectorized, grid-stride) ----------
__global__ void cvt_f32_bf16(const float* __restrict__ in,
                             unsigned short* __restrict__ out, int n4) {
  int stride = gridDim.x * blockDim.x;
  for (int i = blockIdx.x * blockDim.x + threadIdx.x; i < n4; i += stride) {
    float4 f = reinterpret_cast<const float4*>(in)[i];
    ushort4 o;
    o.x = f2bf(f.x); o.y = f2bf(f.y); o.z = f2bf(f.z); o.w = f2bf(f.w);
    reinterpret_cast<ushort4*>(out)[i] = o;
  }
}

// ---------- GEMM: C[M,N] = A[M,K] * B[N,K]^T   (bf16 in, bf16 or f32 out) ----------
// 128x128 block tile, 4 waves (2x2), each wave 64x64 (4x4 frags of 16x16x32 MFMA).
template <bool BF16_OUT>
__global__ __launch_bounds__(256) void gemm_bt(const unsigned short* __restrict__ A,
                                               const unsigned short* __restrict__ B,
                                               void* __restrict__ Cv,
                                               int M, int N, int K) {
  __shared__ unsigned short As[128][40];  // +8 pad: 80B row stride, conflict-light, 16B aligned
  __shared__ unsigned short Bs[128][40];
  const int tid = threadIdx.x;
  const int lane = tid & 63, wid = tid >> 6;
  const int wm = (wid >> 1) * 64, wn = (wid & 1) * 64;
  const int fr = lane & 15, kq = lane >> 4;
  const int arow0 = blockIdx.x * 128;
  const int brow0 = blockIdx.y * 128;
  const int lrow = tid >> 2, lcol = (tid & 3) * 8;

  f32x4 acc[4][4] = {};

  for (int k0 = 0; k0 < K; k0 += 32) {
#pragma unroll
    for (int p = 0; p < 2; p++) {
      int r = p * 64 + lrow;
      *reinterpret_cast<bf16x8*>(&As[r][lcol]) =
          *reinterpret_cast<const bf16x8*>(&A[(size_t)(arow0 + r) * K + k0 + lcol]);
      *reinterpret_cast<bf16x8*>(&Bs[r][lcol]) =
          *reinterpret_cast<const bf16x8*>(&B[(size_t)(brow0 + r) * K + k0 + lcol]);
    }
    __syncthreads();
    bf16x8 af[4], bfr[4];
#pragma unroll
    for (int i = 0; i < 4; i++)
      af[i] = *reinterpret_cast<const bf16x8*>(&As[wm + i * 16 + fr][kq * 8]);
#pragma unroll
    for (int j = 0; j < 4; j++)
      bfr[j] = *reinterpret_cast<const bf16x8*>(&Bs[wn + j * 16 + fr][kq * 8]);
#pragma unroll
    for (int i = 0; i < 4; i++)
#pragma unroll
      for (int j = 0; j < 4; j++)
        acc[i][j] = __builtin_amdgcn_mfma_f32_16x16x32_bf16(af[i], bfr[j], acc[i][j], 0, 0, 0);
    __syncthreads();
  }

#pragma unroll
  for (int i = 0; i < 4; i++) {
#pragma unroll
    for (int j = 0; j < 4; j++) {
#pragma unroll
      for (int r = 0; r < 4; r++) {
        size_t row = (size_t)(arow0 + wm + i * 16 + kq * 4 + r);
        size_t col = (size_t)(brow0 + wn + j * 16 + fr);
        if (BF16_OUT)
          ((unsigned short*)Cv)[row * N + col] = f2bf(acc[i][j][r]);
        else
          ((float*)Cv)[row * N + col] = acc[i][j][r];
      }
    }
  }
}

// ---------- RoPE in-place on Q and K columns of qkv (bf16), Q scaled by 1/8 ----------
__global__ __launch_bounds__(512) void rope_kernel(unsigned short* __restrict__ qkv,
                                                   const int* __restrict__ pos) {
  int m = blockIdx.x;  // b*2048 + s
  int s = m & 2047;
  int t = threadIdx.x;
  int h = t >> 5, p = t & 31;
  float position = (float)pos[s];
  // inv_freq = 10000^(-2p/64) = exp(-p * ln(10000)/32)
  float inv = __expf(-(float)p * (9.210340371976184f / 32.0f));
  float ang = position * inv;
  float c = cosf(ang), sn = sinf(ang);
  size_t base = (size_t)m * 3072 + h * 64 + 2 * p;
  float qe = bf2f(qkv[base]), qo = bf2f(qkv[base + 1]);
  qkv[base]     = f2bf((qe * c - qo * sn) * 0.125f);  // fold 1/sqrt(64)
  qkv[base + 1] = f2bf((qe * sn + qo * c) * 0.125f);
  size_t kb = base + 1024;
  float ke = bf2f(qkv[kb]), ko = bf2f(qkv[kb + 1]);
  qkv[kb]     = f2bf(ke * c - ko * sn);
  qkv[kb + 1] = f2bf(ke * sn + ko * c);
}

// ---------- V transpose: qkv cols [2048,3072) -> Vt[b][h][d][s] ----------
__global__ __launch_bounds__(256) void vtrans_kernel(const unsigned short* __restrict__ qkv,
                                                     unsigned short* __restrict__ vt) {
  int bid = blockIdx.x;          // ((b*16+h)*32 + sb)
  int sb = bid & 31;
  int bh = bid >> 5;             // b*16+h
  int h = bh & 15, b = bh >> 4;
  __shared__ unsigned short tile[64][72];  // [s][d], padded
  int t = threadIdx.x;
  int sl = t >> 2, c0 = (t & 3) * 16;
  const unsigned short* src = qkv + (size_t)(b * 2048 + sb * 64) * 3072 + 2048 + h * 64;
  *reinterpret_cast<bf16x8*>(&tile[sl][c0]) =
      *reinterpret_cast<const bf16x8*>(&src[(size_t)sl * 3072 + c0]);
  *reinterpret_cast<bf16x8*>(&tile[sl][c0 + 8]) =
      *reinterpret_cast<const bf16x8*>(&src[(size_t)sl * 3072 + c0 + 8]);
  __syncthreads();
  int d = t >> 2, s0 = (t & 3) * 16;
  unsigned short* dst = vt + ((size_t)bh * 64 + d) * 2048 + sb * 64 + s0;
  bf16x8 o0, o1;
#pragma unroll
  for (int i = 0; i < 8; i++) {
    o0[i] = (short)tile[s0 + i][d];
    o1[i] = (short)tile[s0 + 8 + i][d];
  }
  *reinterpret_cast<bf16x8*>(dst) = o0;
  *reinterpret_cast<bf16x8*>(dst + 8) = o1;
}

// ---------- causal flash attention ----------
// grid: b(2) * h(16) * qblocks(32); block: 256 (4 waves), wave handles 16 q rows.
__global__ __launch_bounds__(256) void attn_kernel(const unsigned short* __restrict__ qkv,
                                                   const unsigned short* __restrict__ vt,
                                                   unsigned short* __restrict__ Y) {
  int bid = blockIdx.x;
  int qb = bid & 31, h = (bid >> 5) & 15, b = bid >> 9;
  int tid = threadIdx.x, lane = tid & 63, wid = tid >> 6;
  int fr = lane & 15, kq = lane >> 4;
  int qbase = qb * 64 + wid * 16;  // wave's first q row

  const size_t mrow0 = (size_t)b * 2048;
  const unsigned short* Qp = qkv + (mrow0 + qbase) * 3072 + h * 64;
  const unsigned short* Kp = qkv + mrow0 * 3072 + 1024 + h * 64;
  const unsigned short* Vp = vt + ((size_t)(b * 16 + h) * 64) * 2048;  // [d][s]

  // Q fragments (already scaled by 1/8 at rope time)
  bf16x8 qf[2];
#pragma unroll
  for (int ks = 0; ks < 2; ks++)
    qf[ks] = *reinterpret_cast<const bf16x8*>(&Qp[(size_t)fr * 3072 + ks * 32 + kq * 8]);

  f32x4 acc[4] = {};
  float mr[4], lr[4];
#pragma unroll
  for (int r = 0; r < 4; r++) { mr[r] = -1e30f; lr[r] = 0.0f; }

  __shared__ unsigned short Plds[4][16][40];
  __shared__ float Ylds[4][16][64];

  int nkv = (qbase + 15) / 32 + 1;  // causal limit for this wave
  for (int kv = 0; kv < nkv; kv++) {
    int kbase = kv * 32;
    // ---- scores: 16 q x 32 k ----
    f32x4 sc[2] = {};
#pragma unroll
    for (int g = 0; g < 2; g++)
#pragma unroll
      for (int ks = 0; ks < 2; ks++) {
        bf16x8 kf = *reinterpret_cast<const bf16x8*>(
            &Kp[(size_t)(kbase + g * 16 + fr) * 3072 + ks * 32 + kq * 8]);
        sc[g] = __builtin_amdgcn_mfma_f32_16x16x32_bf16(qf[ks], kf, sc[g], 0, 0, 0);
      }
    // ---- mask + online softmax ----
    float p0v[4], p1v[4], scale[4];
#pragma unroll
    for (int r = 0; r < 4; r++) {
      int q = qbase + kq * 4 + r;
      float s0 = sc[0][r]; if (kbase + fr > q)      s0 = -1e30f;
      float s1 = sc[1][r]; if (kbase + 16 + fr > q) s1 = -1e30f;
      float rm = fmaxf(s0, s1);
#pragma unroll
      for (int off = 1; off < 16; off <<= 1) rm = fmaxf(rm, __shfl_xor(rm, off));
      float mn = fmaxf(mr[r], rm);
      float sc_ = __expf(mr[r] - mn);
      float p0 = __expf(s0 - mn), p1 = __expf(s1 - mn);
      float rs = p0 + p1;
#pragma unroll
      for (int off = 1; off < 16; off <<= 1) rs += __shfl_xor(rs, off);
      lr[r] = lr[r] * sc_ + rs;
      mr[r] = mn;
      scale[r] = sc_;
      p0v[r] = p0; p1v[r] = p1;
    }
#pragma unroll
    for (int db = 0; db < 4; db++)
#pragma unroll
      for (int r = 0; r < 4; r++) acc[db][r] *= scale[r];
    // ---- P -> LDS (A-fragment layout round trip) ----
#pragma unroll
    for (int r = 0; r < 4; r++) {
      Plds[wid][kq * 4 + r][fr]      = f2bf(p0v[r]);
      Plds[wid][kq * 4 + r][fr + 16] = f2bf(p1v[r]);
    }
    asm volatile("s_waitcnt lgkmcnt(0)" ::: "memory");
    __builtin_amdgcn_sched_barrier(0);
    bf16x8 pa = *reinterpret_cast<const bf16x8*>(&Plds[wid][fr][kq * 8]);
    // ---- PV ----
#pragma unroll
    for (int db = 0; db < 4; db++) {
      bf16x8 vf = *reinterpret_cast<const bf16x8*>(
          &Vp[(size_t)(db * 16 + fr) * 2048 + kbase + kq * 8]);
      acc[db] = __builtin_amdgcn_mfma_f32_16x16x32_bf16(pa, vf, acc[db], 0, 0, 0);
    }
  }

  // ---- epilogue: normalize, stage in LDS, coalesced bf16 write ----
  float inv[4];
#pragma unroll
  for (int r = 0; r < 4; r++) inv[r] = 1.0f / lr[r];
#pragma unroll
  for (int db = 0; db < 4; db++)
#pragma unroll
    for (int r = 0; r < 4; r++)
      Ylds[wid][kq * 4 + r][db * 16 + fr] = acc[db][r] * inv[r];
  asm volatile("s_waitcnt lgkmcnt(0)" ::: "memory");
  __builtin_amdgcn_sched_barrier(0);
  int row = lane >> 2, c0 = (lane & 3) * 16;
  bf16x8 o0, o1;
#pragma unroll
  for (int i = 0; i < 8; i++) {
    o0[i] = (short)f2bf(Ylds[wid][row][c0 + i]);
    o1[i] = (short)f2bf(Ylds[wid][row][c0 + 8 + i]);
  }
  unsigned short* yp = Y + (mrow0 + qbase + row) * 1024 + h * 64 + c0;
  *reinterpret_cast<bf16x8*>(yp) = o0;
  *reinterpret_cast<bf16x8*>(yp + 8) = o1;
}

// ---------- launch ----------
extern "C" void kernel_launch(void* const* d_in, const int* in_sizes, int n_in,
                              void* d_out, int out_size, void* d_ws, size_t ws_size,
                              hipStream_t stream) {
  const float* x     = (const float*)d_in[0];   // [2,2048,1024]
  const float* w_qkv = (const float*)d_in[1];   // [3072,1024]
  const float* w_o   = (const float*)d_in[2];   // [1024,1024]
  const int*   pos   = (const int*)d_in[3];     // [2048]
  float* out = (float*)d_out;                   // [2,2048,1024] f32

  unsigned char* ws = (unsigned char*)d_ws;
  unsigned short* x_bf    = (unsigned short*)(ws);               //  8,388,608 B
  unsigned short* wqkv_bf = (unsigned short*)(ws + 8388608);     //  6,291,456 B
  unsigned short* wo_bf   = (unsigned short*)(ws + 14680064);    //  2,097,152 B
  unsigned short* qkv     = (unsigned short*)(ws + 16777216);    // 25,165,824 B
  unsigned short* vt      = (unsigned short*)(ws + 41943040);    //  8,388,608 B
  unsigned short* y       = (unsigned short*)(ws + 50331648);    //  8,388,608 B
  // total 58,720,256 B

  cvt_f32_bf16<<<1024, 256, 0, stream>>>(x, x_bf, 4096 * 1024 / 4);
  cvt_f32_bf16<<<1024, 256, 0, stream>>>(w_qkv, wqkv_bf, 3072 * 1024 / 4);
  cvt_f32_bf16<<<512, 256, 0, stream>>>(w_o, wo_bf, 1024 * 1024 / 4);

  gemm_bt<true><<<dim3(32, 24), 256, 0, stream>>>(x_bf, wqkv_bf, (void*)qkv, 4096, 3072, 1024);

  rope_kernel<<<4096, 512, 0, stream>>>(qkv, pos);
  vtrans_kernel<<<1024, 256, 0, stream>>>(qkv, vt);

  attn_kernel<<<1024, 256, 0, stream>>>(qkv, vt, y);

  gemm_bt<false><<<dim3(32, 8), 256, 0, stream>>>(y, wo_bf, (void*)out, 4096, 1024, 1024);
}

// Round 2
// 228.180 us; speedup vs baseline: 1.4097x; 1.4097x over previous
//
#include <hip/hip_runtime.h>

#define DEV __device__ __forceinline__

typedef __attribute__((ext_vector_type(8))) short bf16x8;
typedef __attribute__((ext_vector_type(4))) float f32x4;

// ---------- bf16 helpers (bit-level, RNE) ----------
DEV unsigned short f2bf(float f) {
  union { float f; unsigned int u; } v; v.f = f;
  unsigned int u = v.u;
  unsigned int r = (u + 0x7fffu + ((u >> 16) & 1u)) >> 16;
  return (unsigned short)r;
}
DEV float bf2f(unsigned short h) {
  union { unsigned int u; float f; } v; v.u = ((unsigned int)h) << 16;
  return v.f;
}

// ---------- fp32 -> bf16 convert (vectorized, grid-stride) ----------
__global__ void cvt_f32_bf16(const float* __restrict__ in,
                             unsigned short* __restrict__ out, int n4) {
  int stride = gridDim.x * blockDim.x;
  for (int i = blockIdx.x * blockDim.x + threadIdx.x; i < n4; i += stride) {
    float4 f = reinterpret_cast<const float4*>(in)[i];
    ushort4 o;
    o.x = f2bf(f.x); o.y = f2bf(f.y); o.z = f2bf(f.z); o.w = f2bf(f.w);
    reinterpret_cast<ushort4*>(out)[i] = o;
  }
}

// ---------- GEMM: C[M,N] = A[M,K] * B[N,K]^T   (bf16 in, bf16 or f32 out) ----------
template <bool BF16_OUT>
__global__ __launch_bounds__(256) void gemm_bt(const unsigned short* __restrict__ A,
                                               const unsigned short* __restrict__ B,
                                               void* __restrict__ Cv,
                                               int M, int N, int K) {
  __shared__ unsigned short As[128][40];
  __shared__ unsigned short Bs[128][40];
  const int tid = threadIdx.x;
  const int lane = tid & 63, wid = tid >> 6;
  const int wm = (wid >> 1) * 64, wn = (wid & 1) * 64;
  const int fr = lane & 15, kq = lane >> 4;
  const int arow0 = blockIdx.x * 128;
  const int brow0 = blockIdx.y * 128;
  const int lrow = tid >> 2, lcol = (tid & 3) * 8;

  f32x4 acc[4][4] = {};

  for (int k0 = 0; k0 < K; k0 += 32) {
#pragma unroll
    for (int p = 0; p < 2; p++) {
      int r = p * 64 + lrow;
      *reinterpret_cast<bf16x8*>(&As[r][lcol]) =
          *reinterpret_cast<const bf16x8*>(&A[(size_t)(arow0 + r) * K + k0 + lcol]);
      *reinterpret_cast<bf16x8*>(&Bs[r][lcol]) =
          *reinterpret_cast<const bf16x8*>(&B[(size_t)(brow0 + r) * K + k0 + lcol]);
    }
    __syncthreads();
    bf16x8 af[4], bfr[4];
#pragma unroll
    for (int i = 0; i < 4; i++)
      af[i] = *reinterpret_cast<const bf16x8*>(&As[wm + i * 16 + fr][kq * 8]);
#pragma unroll
    for (int j = 0; j < 4; j++)
      bfr[j] = *reinterpret_cast<const bf16x8*>(&Bs[wn + j * 16 + fr][kq * 8]);
#pragma unroll
    for (int i = 0; i < 4; i++)
#pragma unroll
      for (int j = 0; j < 4; j++)
        acc[i][j] = __builtin_amdgcn_mfma_f32_16x16x32_bf16(af[i], bfr[j], acc[i][j], 0, 0, 0);
    __syncthreads();
  }

#pragma unroll
  for (int i = 0; i < 4; i++) {
#pragma unroll
    for (int j = 0; j < 4; j++) {
#pragma unroll
      for (int r = 0; r < 4; r++) {
        size_t row = (size_t)(arow0 + wm + i * 16 + kq * 4 + r);
        size_t col = (size_t)(brow0 + wn + j * 16 + fr);
        if (BF16_OUT)
          ((unsigned short*)Cv)[row * N + col] = f2bf(acc[i][j][r]);
        else
          ((float*)Cv)[row * N + col] = acc[i][j][r];
      }
    }
  }
}

// ---------- RoPE in-place on Q and K columns of qkv (bf16), Q scaled by 1/8 ----------
__global__ __launch_bounds__(512) void rope_kernel(unsigned short* __restrict__ qkv,
                                                   const int* __restrict__ pos) {
  int m = blockIdx.x;
  int s = m & 2047;
  int t = threadIdx.x;
  int h = t >> 5, p = t & 31;
  float position = (float)pos[s];
  float inv = __expf(-(float)p * (9.210340371976184f / 32.0f));
  float ang = position * inv;
  float c = cosf(ang), sn = sinf(ang);
  size_t base = (size_t)m * 3072 + h * 64 + 2 * p;
  float qe = bf2f(qkv[base]), qo = bf2f(qkv[base + 1]);
  qkv[base]     = f2bf((qe * c - qo * sn) * 0.125f);
  qkv[base + 1] = f2bf((qe * sn + qo * c) * 0.125f);
  size_t kb = base + 1024;
  float ke = bf2f(qkv[kb]), ko = bf2f(qkv[kb + 1]);
  qkv[kb]     = f2bf(ke * c - ko * sn);
  qkv[kb + 1] = f2bf(ke * sn + ko * c);
}

// ---------- V transpose: qkv cols [2048,3072) -> Vt[b][h][d][s] ----------
__global__ __launch_bounds__(256) void vtrans_kernel(const unsigned short* __restrict__ qkv,
                                                     unsigned short* __restrict__ vt) {
  int bid = blockIdx.x;
  int sb = bid & 31;
  int bh = bid >> 5;
  int h = bh & 15, b = bh >> 4;
  __shared__ unsigned short tile[64][72];
  int t = threadIdx.x;
  int sl = t >> 2, c0 = (t & 3) * 16;
  const unsigned short* src = qkv + (size_t)(b * 2048 + sb * 64) * 3072 + 2048 + h * 64;
  *reinterpret_cast<bf16x8*>(&tile[sl][c0]) =
      *reinterpret_cast<const bf16x8*>(&src[(size_t)sl * 3072 + c0]);
  *reinterpret_cast<bf16x8*>(&tile[sl][c0 + 8]) =
      *reinterpret_cast<const bf16x8*>(&src[(size_t)sl * 3072 + c0 + 8]);
  __syncthreads();
  int d = t >> 2, s0 = (t & 3) * 16;
  unsigned short* dst = vt + ((size_t)bh * 64 + d) * 2048 + sb * 64 + s0;
  bf16x8 o0, o1;
#pragma unroll
  for (int i = 0; i < 8; i++) {
    o0[i] = (short)tile[s0 + i][d];
    o1[i] = (short)tile[s0 + 8 + i][d];
  }
  *reinterpret_cast<bf16x8*>(dst) = o0;
  *reinterpret_cast<bf16x8*>(dst + 8) = o1;
}

// ---------- causal flash attention, swapped-operand layout ----------
// grid: 1024 blocks = 32 (b*h) x 32 pairs; block: 256 threads (4 waves).
// Waves 0,1 -> q-tile jt=pair (rows jt*32 + 16*wid..+15);
// waves 2,3 -> q-tile 63-pair. Work per block is constant (causal balance).
// QK^T computed as mfma(K,Q): lane holds 8 scores for ONE q (q = qbase+lane&15),
// k = kbase + g*16 + (lane>>4)*4 + r. Softmax is in-lane; cross-lane only on
// (rare) rescale. PV as mfma(V,P): Y^T lane-local, lane-scalar 1/l normalize.
__global__ __launch_bounds__(256) void attn_kernel(const unsigned short* __restrict__ qkv,
                                                   const unsigned short* __restrict__ vt,
                                                   unsigned short* __restrict__ Y) {
  int bid = blockIdx.x;
  int pair = bid & 31, bh = bid >> 5;
  int h = bh & 15, b = bh >> 4;
  int tid = threadIdx.x, lane = tid & 63, wid = tid >> 6;
  int fr = lane & 15, kq = lane >> 4;
  int jt = (wid < 2) ? pair : (63 - pair);
  int qbase = jt * 32 + (wid & 1) * 16;

  const size_t mrow0 = (size_t)b * 2048;
  const unsigned short* Qp = qkv + (mrow0 + qbase) * 3072 + h * 64;
  const unsigned short* Kp = qkv + mrow0 * 3072 + 1024 + h * 64;
  const unsigned short* Vp = vt + ((size_t)(b * 16 + h) * 64) * 2048;  // [d][s]

  // Q fragments (pre-scaled by 1/8 at rope time). Lane holds Q[qbase+fr][.]
  bf16x8 qf[2];
#pragma unroll
  for (int ks = 0; ks < 2; ks++)
    qf[ks] = *reinterpret_cast<const bf16x8*>(&Qp[(size_t)fr * 3072 + ks * 32 + kq * 8]);

  f32x4 acc[4] = {};            // Y^T: rows d'=db*16+kq*4+r, col q=lane&15
  float mr = -1e30f, lr = 0.0f; // per-lane (per-q) running max / partial sum

  // per-wave packed-P buffer: [q:16][k-pair words:16, padded to 20 (80B rows)]
  __shared__ unsigned int Ppack[4][16][20];
  unsigned int (*pp)[20] = Ppack[wid];

  const int q_lane = qbase + fr;

#define ATTN_STEP(KBASE, MASKED)                                                      \
  {                                                                                   \
    const int kbase_ = (KBASE);                                                      \
    f32x4 sc[2] = {};                                                                 \
    _Pragma("unroll") for (int g = 0; g < 2; g++)                                     \
      _Pragma("unroll") for (int ks = 0; ks < 2; ks++) {                              \
        bf16x8 kf = *reinterpret_cast<const bf16x8*>(                                 \
            &Kp[(size_t)(kbase_ + g * 16 + fr) * 3072 + ks * 32 + kq * 8]);           \
        sc[g] = __builtin_amdgcn_mfma_f32_16x16x32_bf16(kf, qf[ks], sc[g], 0, 0, 0);  \
      }                                                                               \
    float s[8];                                                                       \
    _Pragma("unroll") for (int g = 0; g < 2; g++)                                     \
      _Pragma("unroll") for (int r = 0; r < 4; r++) {                                 \
        float v = sc[g][r];                                                           \
        if (MASKED) {                                                                 \
          int k = kbase_ + g * 16 + kq * 4 + r;                                       \
          if (k > q_lane) v = -1e30f;                                                 \
        }                                                                             \
        s[g * 4 + r] = v;                                                             \
      }                                                                               \
    float rm = s[0];                                                                  \
    _Pragma("unroll") for (int i = 1; i < 8; i++) rm = fmaxf(rm, s[i]);               \
    if (!__all(rm <= mr + 8.0f)) {                                                    \
      float rmf = fmaxf(rm, __shfl_xor(rm, 16));                                      \
      rmf = fmaxf(rmf, __shfl_xor(rmf, 32));                                          \
      float mn = fmaxf(mr, rmf);                                                      \
      float sc_ = __expf(mr - mn);                                                    \
      mr = mn;                                                                        \
      lr *= sc_;                                                                      \
      _Pragma("unroll") for (int db = 0; db < 4; db++)                                \
        _Pragma("unroll") for (int r = 0; r < 4; r++) acc[db][r] *= sc_;              \
    }                                                                                 \
    float p[8];                                                                       \
    float ls = 0.0f;                                                                  \
    _Pragma("unroll") for (int i = 0; i < 8; i++) {                                   \
      p[i] = __expf(s[i] - mr);                                                       \
      ls += p[i];                                                                     \
    }                                                                                 \
    lr += ls;                                                                         \
    _Pragma("unroll") for (int g = 0; g < 2; g++) {                                   \
      unsigned long long w =                                                          \
          (unsigned long long)((unsigned)f2bf(p[g * 4 + 0]) |                         \
                               ((unsigned)f2bf(p[g * 4 + 1]) << 16)) |                \
          ((unsigned long long)((unsigned)f2bf(p[g * 4 + 2]) |                        \
                                ((unsigned)f2bf(p[g * 4 + 3]) << 16))                 \
           << 32);                                                                    \
      *reinterpret_cast<unsigned long long*>(&pp[fr][8 * g + 2 * kq]) = w;            \
    }                                                                                 \
    asm volatile("s_waitcnt lgkmcnt(0)" ::: "memory");                                \
    __builtin_amdgcn_sched_barrier(0);                                                \
    bf16x8 pa = *reinterpret_cast<const bf16x8*>(&pp[fr][4 * kq]);                    \
    _Pragma("unroll") for (int db = 0; db < 4; db++) {                                \
      bf16x8 vf = *reinterpret_cast<const bf16x8*>(                                   \
          &Vp[(size_t)(db * 16 + fr) * 2048 + kbase_ + kq * 8]);                      \
      acc[db] = __builtin_amdgcn_mfma_f32_16x16x32_bf16(vf, pa, acc[db], 0, 0, 0);    \
    }                                                                                 \
  }

  const int nfull = qbase >> 5;  // unmasked 32-wide KV tiles
  for (int kv = 0; kv < nfull; kv++) ATTN_STEP(kv * 32, false);
  ATTN_STEP(nfull * 32, true);
#undef ATTN_STEP

  // epilogue: finish row-sum across the 4 lanes sharing this q, normalize, store
  lr += __shfl_xor(lr, 16);
  lr += __shfl_xor(lr, 32);
  float inv = 1.0f / lr;
  unsigned short* yp = Y + (mrow0 + qbase + fr) * 1024 + h * 64 + kq * 4;
#pragma unroll
  for (int db = 0; db < 4; db++) {
    ushort4 o;
    o.x = f2bf(acc[db][0] * inv);
    o.y = f2bf(acc[db][1] * inv);
    o.z = f2bf(acc[db][2] * inv);
    o.w = f2bf(acc[db][3] * inv);
    *reinterpret_cast<ushort4*>(yp + db * 16) = o;
  }
}

// ---------- launch ----------
extern "C" void kernel_launch(void* const* d_in, const int* in_sizes, int n_in,
                              void* d_out, int out_size, void* d_ws, size_t ws_size,
                              hipStream_t stream) {
  const float* x     = (const float*)d_in[0];   // [2,2048,1024]
  const float* w_qkv = (const float*)d_in[1];   // [3072,1024]
  const float* w_o   = (const float*)d_in[2];   // [1024,1024]
  const int*   pos   = (const int*)d_in[3];     // [2048]
  float* out = (float*)d_out;                   // [2,2048,1024] f32

  unsigned char* ws = (unsigned char*)d_ws;
  unsigned short* x_bf    = (unsigned short*)(ws);               //  8,388,608 B
  unsigned short* wqkv_bf = (unsigned short*)(ws + 8388608);     //  6,291,456 B
  unsigned short* wo_bf   = (unsigned short*)(ws + 14680064);    //  2,097,152 B
  unsigned short* qkv     = (unsigned short*)(ws + 16777216);    // 25,165,824 B
  unsigned short* vt      = (unsigned short*)(ws + 41943040);    //  8,388,608 B
  unsigned short* y       = (unsigned short*)(ws + 50331648);    //  8,388,608 B

  cvt_f32_bf16<<<1024, 256, 0, stream>>>(x, x_bf, 4096 * 1024 / 4);
  cvt_f32_bf16<<<1024, 256, 0, stream>>>(w_qkv, wqkv_bf, 3072 * 1024 / 4);
  cvt_f32_bf16<<<512, 256, 0, stream>>>(w_o, wo_bf, 1024 * 1024 / 4);

  gemm_bt<true><<<dim3(32, 24), 256, 0, stream>>>(x_bf, wqkv_bf, (void*)qkv, 4096, 3072, 1024);

  rope_kernel<<<4096, 512, 0, stream>>>(qkv, pos);
  vtrans_kernel<<<1024, 256, 0, stream>>>(qkv, vt);

  attn_kernel<<<1024, 256, 0, stream>>>(qkv, vt, y);

  gemm_bt<false><<<dim3(32, 8), 256, 0, stream>>>(y, wo_bf, (void*)out, 4096, 1024, 1024);
}

// Round 3
// 156.902 us; speedup vs baseline: 2.0501x; 1.4543x over previous
//
#include <hip/hip_runtime.h>

#define DEV __device__ __forceinline__

typedef __attribute__((ext_vector_type(8))) short bf16x8;
typedef __attribute__((ext_vector_type(4))) float f32x4;

typedef __attribute__((address_space(3))) unsigned int lds_u32;
typedef const __attribute__((address_space(1))) unsigned int glb_u32;

// async global->LDS, 16B per lane; lds dest = wave-uniform base + lane*16
DEV void gload16(const unsigned short* g, unsigned short* l) {
  __builtin_amdgcn_global_load_lds((glb_u32*)g, (lds_u32*)l, 16, 0, 0);
}

// ---------- bf16 helpers (bit-level, RNE) ----------
DEV unsigned short f2bf(float f) {
  union { float f; unsigned int u; } v; v.f = f;
  unsigned int u = v.u;
  unsigned int r = (u + 0x7fffu + ((u >> 16) & 1u)) >> 16;
  return (unsigned short)r;
}
DEV float bf2f(unsigned short h) {
  union { unsigned int u; float f; } v; v.u = ((unsigned int)h) << 16;
  return v.f;
}

// ---------- fp32 -> bf16 convert (vectorized, grid-stride) ----------
__global__ void cvt_f32_bf16(const float* __restrict__ in,
                             unsigned short* __restrict__ out, int n4) {
  int stride = gridDim.x * blockDim.x;
  for (int i = blockIdx.x * blockDim.x + threadIdx.x; i < n4; i += stride) {
    float4 f = reinterpret_cast<const float4*>(in)[i];
    ushort4 o;
    o.x = f2bf(f.x); o.y = f2bf(f.y); o.z = f2bf(f.z); o.w = f2bf(f.w);
    reinterpret_cast<ushort4*>(out)[i] = o;
  }
}

// ---------- GEMM: C[M,N] = A[M,K] * B[N,K]^T   (bf16 in, bf16 or f32 out) ----------
template <bool BF16_OUT>
__global__ __launch_bounds__(256) void gemm_bt(const unsigned short* __restrict__ A,
                                               const unsigned short* __restrict__ B,
                                               void* __restrict__ Cv,
                                               int M, int N, int K) {
  __shared__ unsigned short As[128][40];
  __shared__ unsigned short Bs[128][40];
  const int tid = threadIdx.x;
  const int lane = tid & 63, wid = tid >> 6;
  const int wm = (wid >> 1) * 64, wn = (wid & 1) * 64;
  const int fr = lane & 15, kq = lane >> 4;
  const int arow0 = blockIdx.x * 128;
  const int brow0 = blockIdx.y * 128;
  const int lrow = tid >> 2, lcol = (tid & 3) * 8;

  f32x4 acc[4][4] = {};

  for (int k0 = 0; k0 < K; k0 += 32) {
#pragma unroll
    for (int p = 0; p < 2; p++) {
      int r = p * 64 + lrow;
      *reinterpret_cast<bf16x8*>(&As[r][lcol]) =
          *reinterpret_cast<const bf16x8*>(&A[(size_t)(arow0 + r) * K + k0 + lcol]);
      *reinterpret_cast<bf16x8*>(&Bs[r][lcol]) =
          *reinterpret_cast<const bf16x8*>(&B[(size_t)(brow0 + r) * K + k0 + lcol]);
    }
    __syncthreads();
    bf16x8 af[4], bfr[4];
#pragma unroll
    for (int i = 0; i < 4; i++)
      af[i] = *reinterpret_cast<const bf16x8*>(&As[wm + i * 16 + fr][kq * 8]);
#pragma unroll
    for (int j = 0; j < 4; j++)
      bfr[j] = *reinterpret_cast<const bf16x8*>(&Bs[wn + j * 16 + fr][kq * 8]);
#pragma unroll
    for (int i = 0; i < 4; i++)
#pragma unroll
      for (int j = 0; j < 4; j++)
        acc[i][j] = __builtin_amdgcn_mfma_f32_16x16x32_bf16(af[i], bfr[j], acc[i][j], 0, 0, 0);
    __syncthreads();
  }

#pragma unroll
  for (int i = 0; i < 4; i++) {
#pragma unroll
    for (int j = 0; j < 4; j++) {
#pragma unroll
      for (int r = 0; r < 4; r++) {
        size_t row = (size_t)(arow0 + wm + i * 16 + kq * 4 + r);
        size_t col = (size_t)(brow0 + wn + j * 16 + fr);
        if (BF16_OUT)
          ((unsigned short*)Cv)[row * N + col] = f2bf(acc[i][j][r]);
        else
          ((float*)Cv)[row * N + col] = acc[i][j][r];
      }
    }
  }
}

// ---------- RoPE in-place on Q and K columns of qkv (bf16), Q scaled by 1/8 ----------
__global__ __launch_bounds__(512) void rope_kernel(unsigned short* __restrict__ qkv,
                                                   const int* __restrict__ pos) {
  int m = blockIdx.x;
  int s = m & 2047;
  int t = threadIdx.x;
  int h = t >> 5, p = t & 31;
  float position = (float)pos[s];
  float inv = __expf(-(float)p * (9.210340371976184f / 32.0f));
  float ang = position * inv;
  float c = cosf(ang), sn = sinf(ang);
  size_t base = (size_t)m * 3072 + h * 64 + 2 * p;
  float qe = bf2f(qkv[base]), qo = bf2f(qkv[base + 1]);
  qkv[base]     = f2bf((qe * c - qo * sn) * 0.125f);
  qkv[base + 1] = f2bf((qe * sn + qo * c) * 0.125f);
  size_t kb = base + 1024;
  float ke = bf2f(qkv[kb]), ko = bf2f(qkv[kb + 1]);
  qkv[kb]     = f2bf(ke * c - ko * sn);
  qkv[kb + 1] = f2bf(ke * sn + ko * c);
}

// ---------- V transpose: qkv cols [2048,3072) -> Vt[b][h][d][s] ----------
__global__ __launch_bounds__(256) void vtrans_kernel(const unsigned short* __restrict__ qkv,
                                                     unsigned short* __restrict__ vt) {
  int bid = blockIdx.x;
  int sb = bid & 31;
  int bh = bid >> 5;
  int h = bh & 15, b = bh >> 4;
  __shared__ unsigned short tile[64][72];
  int t = threadIdx.x;
  int sl = t >> 2, c0 = (t & 3) * 16;
  const unsigned short* src = qkv + (size_t)(b * 2048 + sb * 64) * 3072 + 2048 + h * 64;
  *reinterpret_cast<bf16x8*>(&tile[sl][c0]) =
      *reinterpret_cast<const bf16x8*>(&src[(size_t)sl * 3072 + c0]);
  *reinterpret_cast<bf16x8*>(&tile[sl][c0 + 8]) =
      *reinterpret_cast<const bf16x8*>(&src[(size_t)sl * 3072 + c0 + 8]);
  __syncthreads();
  int d = t >> 2, s0 = (t & 3) * 16;
  unsigned short* dst = vt + ((size_t)bh * 64 + d) * 2048 + sb * 64 + s0;
  bf16x8 o0, o1;
#pragma unroll
  for (int i = 0; i < 8; i++) {
    o0[i] = (short)tile[s0 + i][d];
    o1[i] = (short)tile[s0 + 8 + i][d];
  }
  *reinterpret_cast<bf16x8*>(dst) = o0;
  *reinterpret_cast<bf16x8*>(dst + 8) = o1;
}

// ---------- causal flash attention, LDS-staged K/V, swapped-operand MFMA ----------
// grid: 1024 = 32 q-tiles (64 rows, longest-first) x 32 (b*h); block: 4 waves.
// All 4 waves share one q-tile; wave w owns rows [qt*64+16w, +16).
// Per 32-wide KV step: K tile (32x64) and V^T tile (64x32) staged to LDS via
// global_load_lds (linear dest, inverse-swizzled global source), double-buffered.
// QK^T as mfma(K,Q) -> lane-local scores for q=qbase+(lane&15); in-lane softmax
// with defer-max (THR=8); PV as mfma(V,P) -> Y^T lane-local.
__global__ __launch_bounds__(256) void attn_kernel(const unsigned short* __restrict__ qkv,
                                                   const unsigned short* __restrict__ vt,
                                                   unsigned short* __restrict__ Y) {
  int bid = blockIdx.x;
  int bh = bid & 31;                 // bh%8 == bid%8 -> XCD-local heads
  int qt = 31 - (bid >> 5);          // longest q-tiles dispatched first
  int h = bh & 15, b = bh >> 4;
  int tid = threadIdx.x, lane = tid & 63, wid = tid >> 6;
  int fr = lane & 15, kq = lane >> 4;
  int qbase = qt * 64 + wid * 16;

  const size_t mrow0 = (size_t)b * 2048;
  const unsigned short* Qp = qkv + (mrow0 + qbase) * 3072 + h * 64;
  const unsigned short* Kp = qkv + mrow0 * 3072 + 1024 + h * 64;
  const unsigned short* Vp = vt + ((size_t)bh * 64) * 2048;  // [d][s]

  __shared__ unsigned short Klds[2][2048];  // [k:32][d:64] linear, src-swizzled
  __shared__ unsigned short Vlds[2][2048];  // [d:64][s:32] linear, src-swizzled
  __shared__ unsigned int Ppack[4][16][20];
  unsigned int (*pp)[20] = Ppack[wid];

  // Q fragments (pre-scaled by 1/8 at rope time); lane holds Q[qbase+fr][.]
  bf16x8 qf[2];
#pragma unroll
  for (int ks = 0; ks < 2; ks++)
    qf[ks] = *reinterpret_cast<const bf16x8*>(&Qp[(size_t)fr * 3072 + ks * 32 + kq * 8]);

  // staging source addresses (inverse swizzle so swizzled ds_reads see linear data)
  const int krow = tid >> 3, kcg = tid & 7;
  const unsigned short* ksrc =
      Kp + (size_t)krow * 3072 + (size_t)(((kcg ^ (krow & 7)) & 7) * 8);
  const int vj = tid >> 3, vs8 = (tid & 7) ^ (vj & 7);
  const unsigned short* vsrc =
      Vp + (size_t)(2 * vj + (vs8 >> 2)) * 2048 + (size_t)((vs8 & 3) * 8);

  f32x4 acc[4] = {};             // Y^T rows d'=db*16+kq*4+r, col q=lane&15
  float mr = -1e30f, lr = 0.0f;  // per-lane running max / partial sum
  const int q_lane = qbase + fr;

#define STAGE(T)                                                   \
  {                                                                \
    int kb_ = (T) * 32;                                            \
    gload16(ksrc + (size_t)kb_ * 3072, &Klds[(T) & 1][wid * 512]); \
    gload16(vsrc + kb_, &Vlds[(T) & 1][wid * 512]);                \
  }

#define ATTN_STEP(KBASE, MASKED, BI)                                                  \
  {                                                                                   \
    const int kbase_ = (KBASE);                                                       \
    const bool masked_ = (MASKED);                                                    \
    f32x4 sc[2] = {};                                                                 \
    _Pragma("unroll") for (int g = 0; g < 2; g++)                                     \
      _Pragma("unroll") for (int ks = 0; ks < 2; ks++) {                              \
        int R = g * 16 + fr;                                                          \
        bf16x8 kf = *reinterpret_cast<const bf16x8*>(                                 \
            &Klds[BI][R * 64 + (((ks * 4 + kq) ^ (R & 7)) * 8)]);                     \
        sc[g] = __builtin_amdgcn_mfma_f32_16x16x32_bf16(kf, qf[ks], sc[g], 0, 0, 0);  \
      }                                                                               \
    float s[8];                                                                       \
    _Pragma("unroll") for (int g = 0; g < 2; g++)                                     \
      _Pragma("unroll") for (int r = 0; r < 4; r++) {                                 \
        float v = sc[g][r];                                                           \
        if (masked_) {                                                                \
          int k = kbase_ + g * 16 + kq * 4 + r;                                       \
          if (k > q_lane) v = -1e30f;                                                 \
        }                                                                             \
        s[g * 4 + r] = v;                                                             \
      }                                                                               \
    float rm = s[0];                                                                  \
    _Pragma("unroll") for (int i = 1; i < 8; i++) rm = fmaxf(rm, s[i]);               \
    if (!__all(rm <= mr + 8.0f)) {                                                    \
      float rmf = fmaxf(rm, __shfl_xor(rm, 16));                                      \
      rmf = fmaxf(rmf, __shfl_xor(rmf, 32));                                          \
      float mn = fmaxf(mr, rmf);                                                      \
      float sc_ = __expf(mr - mn);                                                    \
      mr = mn;                                                                        \
      lr *= sc_;                                                                      \
      _Pragma("unroll") for (int db = 0; db < 4; db++)                                \
        _Pragma("unroll") for (int r = 0; r < 4; r++) acc[db][r] *= sc_;              \
    }                                                                                 \
    float p[8];                                                                       \
    float ls = 0.0f;                                                                  \
    _Pragma("unroll") for (int i = 0; i < 8; i++) {                                   \
      p[i] = __expf(s[i] - mr);                                                       \
      ls += p[i];                                                                     \
    }                                                                                 \
    lr += ls;                                                                         \
    _Pragma("unroll") for (int g = 0; g < 2; g++) {                                   \
      unsigned long long w =                                                          \
          (unsigned long long)((unsigned)f2bf(p[g * 4 + 0]) |                         \
                               ((unsigned)f2bf(p[g * 4 + 1]) << 16)) |                \
          ((unsigned long long)((unsigned)f2bf(p[g * 4 + 2]) |                        \
                                ((unsigned)f2bf(p[g * 4 + 3]) << 16))                 \
           << 32);                                                                    \
      *reinterpret_cast<unsigned long long*>(&pp[fr][8 * g + 2 * kq]) = w;            \
    }                                                                                 \
    asm volatile("s_waitcnt lgkmcnt(0)" ::: "memory");                                \
    __builtin_amdgcn_sched_barrier(0);                                                \
    bf16x8 pa = *reinterpret_cast<const bf16x8*>(&pp[fr][4 * kq]);                    \
    _Pragma("unroll") for (int db = 0; db < 4; db++) {                                \
      int R = db * 16 + fr;                                                           \
      int j = R >> 1;                                                                 \
      int s8 = (((R & 1) * 4 + kq) ^ (j & 7));                                        \
      bf16x8 vf = *reinterpret_cast<const bf16x8*>(&Vlds[BI][j * 64 + s8 * 8]);       \
      acc[db] = __builtin_amdgcn_mfma_f32_16x16x32_bf16(vf, pa, acc[db], 0, 0, 0);    \
    }                                                                                 \
  }

  const int ntiles = 2 * (qt + 1);
  const int nfull = (qbase + 1) >> 5;  // tiles with no masking for this wave
  STAGE(0);
  for (int t = 0; t < ntiles; ++t) {
    __syncthreads();                    // staged tile t visible to all waves
    if (t + 1 < ntiles) STAGE(t + 1);   // prefetch flies during compute
    ATTN_STEP(t * 32, t >= nfull, t & 1);
  }
#undef ATTN_STEP
#undef STAGE

  // epilogue: finish row-sum across the 4 lanes sharing this q, normalize, store
  lr += __shfl_xor(lr, 16);
  lr += __shfl_xor(lr, 32);
  float inv = 1.0f / lr;
  unsigned short* yp = Y + (mrow0 + qbase + fr) * 1024 + h * 64 + kq * 4;
#pragma unroll
  for (int db = 0; db < 4; db++) {
    ushort4 o;
    o.x = f2bf(acc[db][0] * inv);
    o.y = f2bf(acc[db][1] * inv);
    o.z = f2bf(acc[db][2] * inv);
    o.w = f2bf(acc[db][3] * inv);
    *reinterpret_cast<ushort4*>(yp + db * 16) = o;
  }
}

// ---------- launch ----------
extern "C" void kernel_launch(void* const* d_in, const int* in_sizes, int n_in,
                              void* d_out, int out_size, void* d_ws, size_t ws_size,
                              hipStream_t stream) {
  const float* x     = (const float*)d_in[0];   // [2,2048,1024]
  const float* w_qkv = (const float*)d_in[1];   // [3072,1024]
  const float* w_o   = (const float*)d_in[2];   // [1024,1024]
  const int*   pos   = (const int*)d_in[3];     // [2048]
  float* out = (float*)d_out;                   // [2,2048,1024] f32

  unsigned char* ws = (unsigned char*)d_ws;
  unsigned short* x_bf    = (unsigned short*)(ws);               //  8,388,608 B
  unsigned short* wqkv_bf = (unsigned short*)(ws + 8388608);     //  6,291,456 B
  unsigned short* wo_bf   = (unsigned short*)(ws + 14680064);    //  2,097,152 B
  unsigned short* qkv     = (unsigned short*)(ws + 16777216);    // 25,165,824 B
  unsigned short* vt      = (unsigned short*)(ws + 41943040);    //  8,388,608 B
  unsigned short* y       = (unsigned short*)(ws + 50331648);    //  8,388,608 B

  cvt_f32_bf16<<<1024, 256, 0, stream>>>(x, x_bf, 4096 * 1024 / 4);
  cvt_f32_bf16<<<1024, 256, 0, stream>>>(w_qkv, wqkv_bf, 3072 * 1024 / 4);
  cvt_f32_bf16<<<512, 256, 0, stream>>>(w_o, wo_bf, 1024 * 1024 / 4);

  gemm_bt<true><<<dim3(32, 24), 256, 0, stream>>>(x_bf, wqkv_bf, (void*)qkv, 4096, 3072, 1024);

  rope_kernel<<<4096, 512, 0, stream>>>(qkv, pos);
  vtrans_kernel<<<1024, 256, 0, stream>>>(qkv, vt);

  attn_kernel<<<1024, 256, 0, stream>>>(qkv, vt, y);

  gemm_bt<false><<<dim3(32, 8), 256, 0, stream>>>(y, wo_bf, (void*)out, 4096, 1024, 1024);
}

// Round 4
// 122.809 us; speedup vs baseline: 2.6192x; 1.2776x over previous
//
#include <hip/hip_runtime.h>
#include <math.h>

#define DEV __device__ __forceinline__

typedef __attribute__((ext_vector_type(8))) short bf16x8;
typedef __attribute__((ext_vector_type(4))) float f32x4;
typedef __attribute__((ext_vector_type(4))) unsigned int u32x4;

typedef __attribute__((address_space(3))) unsigned int lds_u32;
typedef const __attribute__((address_space(1))) unsigned int glb_u32;

// async global->LDS, 16B per lane; lds dest = wave-uniform base + lane*16
DEV void gload16(const unsigned short* g, unsigned short* l) {
  __builtin_amdgcn_global_load_lds((glb_u32*)g, (lds_u32*)l, 16, 0, 0);
}

// ---------- bf16 helpers ----------
DEV unsigned short f2bf(float f) {
  union { float f; unsigned int u; } v; v.f = f;
  unsigned int u = v.u;
  unsigned int r = (u + 0x7fffu + ((u >> 16) & 1u)) >> 16;
  return (unsigned short)r;
}
DEV float bf2f(unsigned short h) {
  union { unsigned int u; float f; } v; v.u = ((unsigned int)h) << 16;
  return v.f;
}
DEV unsigned int cvtpk_bf16(float lo, float hi) {
  unsigned int r;
  asm("v_cvt_pk_bf16_f32 %0, %1, %2" : "=v"(r) : "v"(lo), "v"(hi));
  return r;
}

// ---------- fp32 -> bf16 convert ----------
__global__ void cvt_f32_bf16(const float* __restrict__ in,
                             unsigned short* __restrict__ out, int n4) {
  int stride = gridDim.x * blockDim.x;
  for (int i = blockIdx.x * blockDim.x + threadIdx.x; i < n4; i += stride) {
    float4 f = reinterpret_cast<const float4*>(in)[i];
    ushort4 o;
    o.x = f2bf(f.x); o.y = f2bf(f.y); o.z = f2bf(f.z); o.w = f2bf(f.w);
    reinterpret_cast<ushort4*>(out)[i] = o;
  }
}

// ---------- GEMM (m97 structure): C[M,N] = A[M,K] * B[N,K]^T ----------
// 128x128 tile, BK=32, 4 waves 2x2, global_load_lds staging, double-buffered.
template <bool BF16_OUT>
__global__ __launch_bounds__(256) void gemm_bt(const unsigned short* __restrict__ A,
                                               const unsigned short* __restrict__ B,
                                               void* __restrict__ Cv,
                                               int M, int N, int K) {
  __shared__ unsigned short Ab[2][4096];  // [128][32] linear
  __shared__ unsigned short Bb[2][4096];
  const int tid = threadIdx.x;
  const int lane = tid & 63, wid = tid >> 6;
  const int wm = (wid >> 1) * 64, wn = (wid & 1) * 64;
  const int fr = lane & 15, kq = lane >> 4;
  const int arow0 = blockIdx.x * 128;
  const int brow0 = blockIdx.y * 128;

  // staging: lane covers row = wid*16 + lane/4 (+64 for call 2), 8-short slot lane&3
  const int srow = wid * 16 + (lane >> 2), sslot = (lane & 3) * 8;
  const unsigned short* asrc = A + (size_t)(arow0 + srow) * K + sslot;
  const unsigned short* bsrc = B + (size_t)(brow0 + srow) * K + sslot;

  f32x4 acc[4][4] = {};
  const int nk = K >> 5;

  gload16(asrc, &Ab[0][wid * 512]);
  gload16(asrc + (size_t)64 * K, &Ab[0][2048 + wid * 512]);
  gload16(bsrc, &Bb[0][wid * 512]);
  gload16(bsrc + (size_t)64 * K, &Bb[0][2048 + wid * 512]);

  for (int ks = 0; ks < nk; ks++) {
    __syncthreads();
    if (ks + 1 < nk) {
      int o = (ks + 1) * 32, bi = (ks + 1) & 1;
      gload16(asrc + o, &Ab[bi][wid * 512]);
      gload16(asrc + (size_t)64 * K + o, &Ab[bi][2048 + wid * 512]);
      gload16(bsrc + o, &Bb[bi][wid * 512]);
      gload16(bsrc + (size_t)64 * K + o, &Bb[bi][2048 + wid * 512]);
    }
    int bi = ks & 1;
    bf16x8 af[4], bfr[4];
#pragma unroll
    for (int i = 0; i < 4; i++)
      af[i] = *reinterpret_cast<const bf16x8*>(&Ab[bi][(wm + i * 16 + fr) * 32 + kq * 8]);
#pragma unroll
    for (int j = 0; j < 4; j++)
      bfr[j] = *reinterpret_cast<const bf16x8*>(&Bb[bi][(wn + j * 16 + fr) * 32 + kq * 8]);
#pragma unroll
    for (int i = 0; i < 4; i++)
#pragma unroll
      for (int j = 0; j < 4; j++)
        acc[i][j] = __builtin_amdgcn_mfma_f32_16x16x32_bf16(af[i], bfr[j], acc[i][j], 0, 0, 0);
  }

#pragma unroll
  for (int i = 0; i < 4; i++) {
#pragma unroll
    for (int j = 0; j < 4; j++) {
#pragma unroll
      for (int r = 0; r < 4; r++) {
        size_t row = (size_t)(arow0 + wm + i * 16 + kq * 4 + r);
        size_t col = (size_t)(brow0 + wn + j * 16 + fr);
        if (BF16_OUT)
          ((unsigned short*)Cv)[row * N + col] = f2bf(acc[i][j][r]);
        else
          ((float*)Cv)[row * N + col] = acc[i][j][r];
      }
    }
  }
}

// ---------- RoPE in-place on Q,K of qkv; Q scaled by 0.125*log2(e) (exp2 softmax) ----------
__global__ __launch_bounds__(256) void rope_kernel(unsigned short* __restrict__ qkv,
                                                   const int* __restrict__ pos) {
  int m = blockIdx.x;
  int s = m & 2047;
  int t = threadIdx.x;
  __shared__ float Cl[32], Sl[32];
  if (t < 32) {
    float position = (float)pos[s];
    // inv_freq = 10000^(-p/32)
    float inv = __expf(-(float)t * (9.210340371976184f / 32.0f));
    float ang = position * inv;
    Cl[t] = cosf(ang);
    Sl[t] = sinf(ang);
  }
  __syncthreads();
  const float QS = 0.18033688011112042f;  // 1/8 * log2(e)
  int h = t >> 4, g = t & 15;             // 2 pairs per thread
  float c0 = Cl[2 * g], s0 = Sl[2 * g], c1 = Cl[2 * g + 1], s1 = Sl[2 * g + 1];
  size_t base = (size_t)m * 3072 + h * 64 + 4 * g;
  ushort4 qv = *reinterpret_cast<ushort4*>(&qkv[base]);
  float qe0 = bf2f(qv.x), qo0 = bf2f(qv.y), qe1 = bf2f(qv.z), qo1 = bf2f(qv.w);
  qv.x = f2bf((qe0 * c0 - qo0 * s0) * QS);
  qv.y = f2bf((qe0 * s0 + qo0 * c0) * QS);
  qv.z = f2bf((qe1 * c1 - qo1 * s1) * QS);
  qv.w = f2bf((qe1 * s1 + qo1 * c1) * QS);
  *reinterpret_cast<ushort4*>(&qkv[base]) = qv;
  size_t kb = base + 1024;
  ushort4 kv = *reinterpret_cast<ushort4*>(&qkv[kb]);
  float ke0 = bf2f(kv.x), ko0 = bf2f(kv.y), ke1 = bf2f(kv.z), ko1 = bf2f(kv.w);
  kv.x = f2bf(ke0 * c0 - ko0 * s0);
  kv.y = f2bf(ke0 * s0 + ko0 * c0);
  kv.z = f2bf(ke1 * c1 - ko1 * s1);
  kv.w = f2bf(ke1 * s1 + ko1 * c1);
  *reinterpret_cast<ushort4*>(&qkv[kb]) = kv;
}

// ---------- V transpose with pi-permuted s: vt[b][h][d][p], within each 32-block
// of s: element s=32A+16a+4b+c stored at p=32A+8b+4a+c (matches QK^T register order) ----------
__global__ __launch_bounds__(256) void vtrans_kernel(const unsigned short* __restrict__ qkv,
                                                     unsigned short* __restrict__ vt) {
  int bid = blockIdx.x;
  int sb = bid & 31;
  int bh = bid >> 5;
  int h = bh & 15, b = bh >> 4;
  __shared__ unsigned short tile[64][72];
  int t = threadIdx.x;
  int sl = t >> 2, c0 = (t & 3) * 16;
  const unsigned short* src = qkv + (size_t)(b * 2048 + sb * 64) * 3072 + 2048 + h * 64;
  *reinterpret_cast<bf16x8*>(&tile[sl][c0]) =
      *reinterpret_cast<const bf16x8*>(&src[(size_t)sl * 3072 + c0]);
  *reinterpret_cast<bf16x8*>(&tile[sl][c0 + 8]) =
      *reinterpret_cast<const bf16x8*>(&src[(size_t)sl * 3072 + c0 + 8]);
  __syncthreads();
  int d = t >> 2, p0 = (t & 3) * 16;
  unsigned short* dst = vt + ((size_t)bh * 64 + d) * 2048 + sb * 64 + p0;
  bf16x8 o0, o1;
#pragma unroll
  for (int i = 0; i < 8; i++) {
    int p = p0 + i;
    int s_in = (p & 32) + ((p >> 2) & 1) * 16 + ((p >> 3) & 3) * 4 + (p & 3);
    o0[i] = (short)tile[s_in][d];
  }
#pragma unroll
  for (int i = 0; i < 8; i++) {
    int p = p0 + 8 + i;
    int s_in = (p & 32) + ((p >> 2) & 1) * 16 + ((p >> 3) & 3) * 4 + (p & 3);
    o1[i] = (short)tile[s_in][d];
  }
  *reinterpret_cast<bf16x8*>(dst) = o0;
  *reinterpret_cast<bf16x8*>(dst + 8) = o1;
}

// ---------- causal flash attention: KVBLK=64, register-resident P ----------
// grid: 1024 = 32 q-tiles (64 rows, longest-first) x 32 bh; 4 waves/block.
// QK^T as mfma(K,Q): lane (fr,kq) holds scores for q=qbase+fr, k=64t+16g+4kq+r.
// P stays in registers (cvt_pk pairs, natural order == pi-permuted V layout).
// PV as mfma(V,P) with V staged in pi-permuted LDS: no cross-lane P movement.
__global__ __launch_bounds__(256, 4) void attn_kernel(const unsigned short* __restrict__ qkv,
                                                      const unsigned short* __restrict__ vt,
                                                      unsigned short* __restrict__ Y) {
  int bid = blockIdx.x;
  int bh = bid & 31;
  int qt = 31 - (bid >> 5);  // longest first
  int h = bh & 15, b = bh >> 4;
  int tid = threadIdx.x, lane = tid & 63, wid = tid >> 6;
  int fr = lane & 15, kq = lane >> 4;
  int qbase = qt * 64 + wid * 16;

  const size_t mrow0 = (size_t)b * 2048;
  const unsigned short* Qp = qkv + (mrow0 + qbase) * 3072 + h * 64;
  const unsigned short* Kp = qkv + mrow0 * 3072 + 1024 + h * 64;
  const unsigned short* Vp = vt + ((size_t)bh * 64) * 2048;  // [d][p]

  __shared__ unsigned short Klds[2][4096];  // [k:64][d:64], chunk-XOR swizzled
  __shared__ unsigned short Vlds[2][4096];  // [d:64][p:64], chunk-XOR swizzled

  // Q fragments (pre-scaled by 0.125*log2e at rope)
  bf16x8 qf[2];
#pragma unroll
  for (int ks = 0; ks < 2; ks++)
    qf[ks] = *reinterpret_cast<const bf16x8*>(&Qp[(size_t)fr * 3072 + ks * 32 + kq * 8]);

  // staging source (inverse chunk swizzle: LDS chunk s16 holds global chunk s16^(row&7))
  const int srow = tid >> 3;
  const int schunk = (tid & 7) ^ (srow & 7);
  const unsigned short* ksrc = Kp + (size_t)srow * 3072 + schunk * 8;
  const unsigned short* vsrc = Vp + (size_t)srow * 2048 + schunk * 8;

  f32x4 acc[4] = {};             // Y^T rows d=db*16+4kq+r, col q=qbase+fr
  float mr = -1e30f, lr = 0.0f;  // per-lane running max (log2 domain) / partial sum
  const int q_lane = qbase + fr;
  const int ntiles = qt + 1;

#define STAGE(T)                                                        \
  {                                                                     \
    int bi_ = (T) & 1;                                                  \
    size_t ko_ = (size_t)(T) * 64 * 3072;                               \
    int vo_ = (T) * 64;                                                 \
    gload16(ksrc + ko_, &Klds[bi_][wid * 512]);                         \
    gload16(ksrc + ko_ + (size_t)32 * 3072, &Klds[bi_][2048 + wid * 512]); \
    gload16(vsrc + vo_, &Vlds[bi_][wid * 512]);                         \
    gload16(vsrc + vo_ + 32 * 2048, &Vlds[bi_][2048 + wid * 512]);      \
  }

  STAGE(0);
  for (int t = 0; t < ntiles; ++t) {
    __syncthreads();
    if (t + 1 < ntiles) STAGE(t + 1);
    const int bi_ = t & 1;
    const bool masked_ = (t == qt);
    const int kbase_ = t * 64;

    // ---- QK^T: 8 MFMA, 4 independent chains ----
    f32x4 sc[4] = {};
    __builtin_amdgcn_s_setprio(1);
#pragma unroll
    for (int g = 0; g < 4; g++) {
      int R = g * 16 + fr;
#pragma unroll
      for (int ks = 0; ks < 2; ks++) {
        bf16x8 kf = *reinterpret_cast<const bf16x8*>(
            &Klds[bi_][R * 64 + ((4 * ks + kq) ^ (R & 7)) * 8]);
        sc[g] = __builtin_amdgcn_mfma_f32_16x16x32_bf16(kf, qf[ks], sc[g], 0, 0, 0);
      }
    }
    __builtin_amdgcn_s_setprio(0);

    // ---- extract + mask ----
    float s[16];
#pragma unroll
    for (int g = 0; g < 4; g++)
#pragma unroll
      for (int r = 0; r < 4; r++) {
        float v = sc[g][r];
        if (masked_) {
          int k = kbase_ + g * 16 + kq * 4 + r;
          if (k > q_lane) v = -1e30f;
        }
        s[g * 4 + r] = v;
      }

    // ---- in-lane softmax (log2 domain), defer-max ----
    float m8[8];
#pragma unroll
    for (int i = 0; i < 8; i++) m8[i] = fmaxf(s[2 * i], s[2 * i + 1]);
    float m4a = fmaxf(fmaxf(m8[0], m8[1]), fmaxf(m8[2], m8[3]));
    float m4b = fmaxf(fmaxf(m8[4], m8[5]), fmaxf(m8[6], m8[7]));
    float rm = fmaxf(m4a, m4b);
    if (!__all(rm <= mr + 8.0f)) {
      float rmf = fmaxf(rm, __shfl_xor(rm, 16));
      rmf = fmaxf(rmf, __shfl_xor(rmf, 32));
      float mn = fmaxf(mr, rmf);
      float scl = exp2f(mr - mn);
      mr = mn;
      lr *= scl;
#pragma unroll
      for (int db = 0; db < 4; db++)
#pragma unroll
        for (int r = 0; r < 4; r++) acc[db][r] *= scl;
    }
#pragma unroll
    for (int i = 0; i < 16; i++) s[i] = exp2f(s[i] - mr);
    float a8[8];
#pragma unroll
    for (int i = 0; i < 8; i++) a8[i] = s[2 * i] + s[2 * i + 1];
    float a4a = (a8[0] + a8[1]) + (a8[2] + a8[3]);
    float a4b = (a8[4] + a8[5]) + (a8[6] + a8[7]);
    lr += a4a + a4b;

    // ---- P -> bf16 in registers (order matches pi-permuted V) ----
    u32x4 W0 = {cvtpk_bf16(s[0], s[1]), cvtpk_bf16(s[2], s[3]),
                cvtpk_bf16(s[4], s[5]), cvtpk_bf16(s[6], s[7])};
    u32x4 W1 = {cvtpk_bf16(s[8], s[9]), cvtpk_bf16(s[10], s[11]),
                cvtpk_bf16(s[12], s[13]), cvtpk_bf16(s[14], s[15])};
    bf16x8 pa0 = *reinterpret_cast<bf16x8*>(&W0);
    bf16x8 pa1 = *reinterpret_cast<bf16x8*>(&W1);

    // ---- PV: 8 MFMA ----
    __builtin_amdgcn_s_setprio(1);
#pragma unroll
    for (int db = 0; db < 4; db++) {
      int d = db * 16 + fr;
      bf16x8 vf0 = *reinterpret_cast<const bf16x8*>(
          &Vlds[bi_][d * 64 + (kq ^ (d & 7)) * 8]);
      acc[db] = __builtin_amdgcn_mfma_f32_16x16x32_bf16(vf0, pa0, acc[db], 0, 0, 0);
      bf16x8 vf1 = *reinterpret_cast<const bf16x8*>(
          &Vlds[bi_][d * 64 + ((4 + kq) ^ (d & 7)) * 8]);
      acc[db] = __builtin_amdgcn_mfma_f32_16x16x32_bf16(vf1, pa1, acc[db], 0, 0, 0);
    }
    __builtin_amdgcn_s_setprio(0);
  }
#undef STAGE

  // ---- epilogue ----
  lr += __shfl_xor(lr, 16);
  lr += __shfl_xor(lr, 32);
  float inv = 1.0f / lr;
  unsigned short* yp = Y + (mrow0 + qbase + fr) * 1024 + h * 64 + kq * 4;
#pragma unroll
  for (int db = 0; db < 4; db++) {
    ushort4 o;
    o.x = f2bf(acc[db][0] * inv);
    o.y = f2bf(acc[db][1] * inv);
    o.z = f2bf(acc[db][2] * inv);
    o.w = f2bf(acc[db][3] * inv);
    *reinterpret_cast<ushort4*>(yp + db * 16) = o;
  }
}

// ---------- launch ----------
extern "C" void kernel_launch(void* const* d_in, const int* in_sizes, int n_in,
                              void* d_out, int out_size, void* d_ws, size_t ws_size,
                              hipStream_t stream) {
  const float* x     = (const float*)d_in[0];   // [2,2048,1024]
  const float* w_qkv = (const float*)d_in[1];   // [3072,1024]
  const float* w_o   = (const float*)d_in[2];   // [1024,1024]
  const int*   pos   = (const int*)d_in[3];     // [2048]
  float* out = (float*)d_out;                   // [2,2048,1024] f32

  unsigned char* ws = (unsigned char*)d_ws;
  unsigned short* x_bf    = (unsigned short*)(ws);               //  8,388,608 B
  unsigned short* wqkv_bf = (unsigned short*)(ws + 8388608);     //  6,291,456 B
  unsigned short* wo_bf   = (unsigned short*)(ws + 14680064);    //  2,097,152 B
  unsigned short* qkv     = (unsigned short*)(ws + 16777216);    // 25,165,824 B
  unsigned short* vt      = (unsigned short*)(ws + 41943040);    //  8,388,608 B
  unsigned short* y       = (unsigned short*)(ws + 50331648);    //  8,388,608 B

  cvt_f32_bf16<<<1024, 256, 0, stream>>>(x, x_bf, 4096 * 1024 / 4);
  cvt_f32_bf16<<<1024, 256, 0, stream>>>(w_qkv, wqkv_bf, 3072 * 1024 / 4);
  cvt_f32_bf16<<<512, 256, 0, stream>>>(w_o, wo_bf, 1024 * 1024 / 4);

  gemm_bt<true><<<dim3(32, 24), 256, 0, stream>>>(x_bf, wqkv_bf, (void*)qkv, 4096, 3072, 1024);

  rope_kernel<<<4096, 256, 0, stream>>>(qkv, pos);
  vtrans_kernel<<<1024, 256, 0, stream>>>(qkv, vt);

  attn_kernel<<<1024, 256, 0, stream>>>(qkv, vt, y);

  gemm_bt<false><<<dim3(32, 8), 256, 0, stream>>>(y, wo_bf, (void*)out, 4096, 1024, 1024);
}